// Round 12
// baseline (19.019 us; speedup 1.0000x reference)
//
#include <hip/hip_runtime.h>
#include <hip/hip_bf16.h>

#define RAD 5
#define DIL 6
#define KS 11            // 2*RAD+1
#define PADW 30          // RAD*DIL
#define TOPK 8
#define TILEW 320        // vote tile: 316 used cols (256 + 60 halo), padded
#define GTW 288          // depth/disp tile width (286 used)

// Problem shape (fixed by reference setup_inputs)
constexpr int B = 2;
constexpr int H = 256;
constexpr int W = 512;
constexpr int HW = H * W;
constexpr int NBLK = 1024;                 // B*H*(W/256)
constexpr double TOTAL_CNT = (double)B * H * W * TOPK;   // 2,097,152

// ---------------------------------------------------------------------------
// Straight-line sorting-network primitives over NAMED registers (round-5's
// VGPR=32 proved arrayed/looped selection goes to scratch).
// ---------------------------------------------------------------------------
#define CE(a,b) { const unsigned _l = min(a,b); const unsigned _h = max(a,b); (a)=_l; (b)=_h; }

// Batcher odd-even mergesort for 8 (19 CE), ascending. Proven exact (r2..r10).
#define SORT8M(k0,k1,k2,k3,k4,k5,k6,k7) \
  CE(k0,k1) CE(k2,k3) CE(k4,k5) CE(k6,k7) \
  CE(k0,k2) CE(k1,k3) CE(k4,k6) CE(k5,k7) \
  CE(k1,k2) CE(k5,k6) \
  CE(k0,k4) CE(k1,k5) CE(k2,k6) CE(k3,k7) \
  CE(k2,k4) CE(k3,k5) \
  CE(k1,k2) CE(k3,k4) CE(k5,k6)

// b (sorted asc) := sorted lowest-8 of union(b, c) where c sorted asc.
#define MERGELOW8M(b0,b1,b2,b3,b4,b5,b6,b7) { \
  unsigned t0=min(b0,c7), t1=min(b1,c6), t2=min(b2,c5), t3=min(b3,c4); \
  unsigned t4=min(b4,c3), t5=min(b5,c2), t6=min(b6,c1), t7=min(b7,c0); \
  CE(t0,t4) CE(t1,t5) CE(t2,t6) CE(t3,t7) \
  CE(t0,t2) CE(t1,t3) CE(t4,t6) CE(t5,t7) \
  CE(t0,t1) CE(t2,t3) CE(t4,t5) CE(t6,t7) \
  b0=t0; b1=t1; b2=t2; b3=t3; b4=t4; b5=t5; b6=t6; b7=t7; }

// Raw tap read at compile-time tap T: 32-bit dword row base (VGPR) +
// compile-time dword offset (KX*6 <= 60, byte 240) -> ds_read2_b32-mergeable.
// OOB taps read the staged 1.0f sentinel (ranks after all votes < 1.0).
template<int T>
__device__ __forceinline__ unsigned rawtap(const float (&vt)[KS * TILEW],
                                           const unsigned (&rbase)[KS]) {
    constexpr int KY = T / KS;
    constexpr int KX = T % KS;
    return __float_as_uint(vt[rbase[KY] + KX * DIL]);
}

// Pair key: (min of raws) masked, pair index in low 7 bits.
// min-then-mask == mask-then-min for a top-25-bit mask (gap 128 > low bits).
#define PAIRK(P) ((min(rawtap<2*(P)>(vt, rbase), rawtap<2*(P)+1>(vt, rbase)) & 0xFFFFFF80u) | (unsigned)(P))

#define LOADG(G) \
  c0 = PAIRK(8*(G)+0); c1 = PAIRK(8*(G)+1); c2 = PAIRK(8*(G)+2); c3 = PAIRK(8*(G)+3); \
  c4 = PAIRK(8*(G)+4); c5 = PAIRK(8*(G)+5); c6 = PAIRK(8*(G)+6); c7 = PAIRK(8*(G)+7); \
  SORT8M(c0,c1,c2,c3,c4,c5,c6,c7)

// Stage-C member key for runtime tap t (<=121): sentinel tile -> no bounds
// test. t=121 (partner of self-paired 120) clamped for address, discarded.
__device__ __forceinline__ unsigned member_key_lds(const float (&vt)[KS * TILEW],
                                                   int tid, unsigned t) {
    const unsigned tc = min(t, 120u);
    const int ky = (int)((tc * 373u) >> 12);     // floor(tc/11), exact
    const int kx = (int)tc - ky * KS;
    const unsigned raw = __float_as_uint(vt[ky * TILEW + tid + kx * DIL]);
    return (raw & 0xFFFFFF80u) | tc;
}

#define REBUILD(BS, MA, MB) { \
  const unsigned _p = (BS) & 127u; \
  MA = member_key_lds(vt, tid, _p * 2u); \
  const unsigned _mb = member_key_lds(vt, tid, _p * 2u + 1u); \
  MB = (_p == 60u) ? 0xFFFFFFFFu : _mb; }

// Gathered loss term from LDS depth/disp tiles. Selected taps are provably
// in-bounds (OOB votes rank last), so NO clamps: tile row = ky (pre-clamped
// staging = replicate pad), col = tid + kx*6 + xadj.
__device__ __forceinline__ float loss_term(const float (&dt)[KS * GTW],
                                           const float (&st)[KS * GTW],
                                           float dC, float sC,
                                           int tid, int xadj, unsigned key) {
    const unsigned idx = key & 127u;
    const int ky = (int)((idx * 373u) >> 12);
    const int kx = (int)idx - ky * KS;
    const int a  = ky * GTW + tid + kx * DIL + xadj;
    const float dN = dt[a];
    const float sN = st[a];
    const float dg = dC - dN;
    const float sg = sC - sN;
    const float dd = sg * __builtin_amdgcn_rcpf(fabsf(sg) + 1e-8f);
    const float aa = fmaxf(fabsf(dg) - 1.0f, 0.0f);
    const float m  = aa * __builtin_amdgcn_rcpf(1.0f + aa);
    const float dw = copysignf(m, dg);
    const float dv = __log2f(fmaf(sg, sg, 1.0f)) * 0.69314718056f;
    return fmaxf(-(dw * dd) * dv, 0.0f);
}

// ---------------------------------------------------------------------------
// Stage 1: sentinel-halo LDS vote tile + clamped LDS depth/disp tiles;
// pair-min-pruned bottom-8 selection (straight-line, proven exact); gather
// entirely from LDS; one partial per block. LDS = 39.4 KB -> 4 blocks/CU;
// __launch_bounds__(256,4) pins VGPR <= 128 for single-pass occupancy.
// ---------------------------------------------------------------------------
__global__ __launch_bounds__(256, 4) void lrl_main(
    const float* __restrict__ disp,
    const float* __restrict__ depth,
    const float* __restrict__ vote,
    float* __restrict__ partials)
{
    const int tid = threadIdx.x;
    const int blk = blockIdx.x;                // 0 .. NBLK-1
    const int row = blk >> 1;                  // b*H + h
    const int half= blk & 1;
    const int w   = (half << 8) + tid;         // 0..511
    const int b   = row >> 8;
    const int h   = row & (H - 1);

    const float* __restrict__ vb = vote  + b * HW;
    const float* __restrict__ db = depth + b * HW;
    const float* __restrict__ sb = disp  + b * HW;

    // Center values (issue early, overlap staging).
    const float dC = db[h * W + w];
    const float sC = sb[h * W + w];

    // ---- Stage tiles ------------------------------------------------------
    // vote: 11 rows x 320 cols, OOB rows/cols = 1.0f sentinel.
    // depth/disp: 11 clamped rows x 286 clamped cols (= replicate padding).
    __shared__ float vt[KS * TILEW];
    __shared__ float dt[KS * GTW];
    __shared__ float st[KS * GTW];
    const int xstart = half ? 226 : 0;
    const int tclo   = half ? 0 : 30;
    const int tcsent = half ? 286 : 0;
#pragma unroll
    for (int ky = 0; ky < KS; ++ky) {
        const int y  = h + ky * DIL - PADW;    // block-uniform
        const int yc = min(max(y, 0), H - 1);
        if (tid < 143) {
            const float2 dv = *(const float2*)(db + yc * W + xstart + 2 * tid);
            const float2 sv = *(const float2*)(sb + yc * W + xstart + 2 * tid);
            *(float2*)&dt[ky * GTW + 2 * tid] = dv;
            *(float2*)&st[ky * GTW + 2 * tid] = sv;
            float2 vv;
            if ((unsigned)y < (unsigned)H)
                vv = *(const float2*)(vb + y * W + xstart + 2 * tid);
            else
                vv = make_float2(1.0f, 1.0f);
            *(float2*)&vt[ky * TILEW + tclo + 2 * tid] = vv;
        } else if (tid < 158) {
            const int j = tid - 143;
            *(float2*)&vt[ky * TILEW + tcsent + 2 * j] = make_float2(1.0f, 1.0f);
        }
    }

    // Per-row 32-bit dword bases (constexpr-indexed -> registers).
    unsigned rbase[KS];
#pragma unroll
    for (int ky = 0; ky < KS; ++ky) rbase[ky] = ky * TILEW + tid;

    const int xadj = half ? 0 : -30;           // gather col adjust (uniform)

    __syncthreads();

    // ---- Stages A+B: 61 pair-min keys -> sorted low-8 (named registers) ---
    unsigned b0,b1,b2,b3,b4,b5,b6,b7, c0,c1,c2,c3,c4,c5,c6,c7;
    LOADG(0);
    b0=c0; b1=c1; b2=c2; b3=c3; b4=c4; b5=c5; b6=c6; b7=c7;
    LOADG(1); MERGELOW8M(b0,b1,b2,b3,b4,b5,b6,b7);
    LOADG(2); MERGELOW8M(b0,b1,b2,b3,b4,b5,b6,b7);
    LOADG(3); MERGELOW8M(b0,b1,b2,b3,b4,b5,b6,b7);
    LOADG(4); MERGELOW8M(b0,b1,b2,b3,b4,b5,b6,b7);
    LOADG(5); MERGELOW8M(b0,b1,b2,b3,b4,b5,b6,b7);
    LOADG(6); MERGELOW8M(b0,b1,b2,b3,b4,b5,b6,b7);
    // Leftover pairs 56..59 (taps 112..119) + self-paired tap 120 (pair 60).
    c0 = PAIRK(56); c1 = PAIRK(57); c2 = PAIRK(58); c3 = PAIRK(59);
    c4 = (rawtap<120>(vt, rbase) & 0xFFFFFF80u) | 60u;
    c5 = 0xFFFFFFFFu; c6 = 0xFFFFFFFFu; c7 = 0xFFFFFFFFu;
    SORT8M(c0,c1,c2,c3,c4,c5,c6,c7);
    MERGELOW8M(b0,b1,b2,b3,b4,b5,b6,b7);   // b = sorted low-8 pair keys

    // ---- Stage C: rebuild the 16 members of the 8 surviving pairs ---------
    unsigned a0,a1,a2,a3,a4,a5,a6,a7, e0,e1,e2,e3,e4,e5,e6,e7;
    REBUILD(b0, a0, e0); REBUILD(b1, a1, e1); REBUILD(b2, a2, e2); REBUILD(b3, a3, e3);
    REBUILD(b4, a4, e4); REBUILD(b5, a5, e5); REBUILD(b6, a6, e6); REBUILD(b7, a7, e7);
    SORT8M(a0,a1,a2,a3,a4,a5,a6,a7);
    SORT8M(e0,e1,e2,e3,e4,e5,e6,e7);
    // ---- Stage D: bitonic lower half -> exact bottom-8 multiset -----------
    const unsigned f0 = min(a0,e7), f1 = min(a1,e6), f2 = min(a2,e5), f3 = min(a3,e4);
    const unsigned f4 = min(a4,e3), f5 = min(a5,e2), f6 = min(a6,e1), f7 = min(a7,e0);

    // ---- Gather + loss terms, all from LDS tiles --------------------------
    float acc = loss_term(dt, st, dC, sC, tid, xadj, f0)
              + loss_term(dt, st, dC, sC, tid, xadj, f1)
              + loss_term(dt, st, dC, sC, tid, xadj, f2)
              + loss_term(dt, st, dC, sC, tid, xadj, f3)
              + loss_term(dt, st, dC, sC, tid, xadj, f4)
              + loss_term(dt, st, dC, sC, tid, xadj, f5)
              + loss_term(dt, st, dC, sC, tid, xadj, f6)
              + loss_term(dt, st, dC, sC, tid, xadj, f7);

    // Block reduction: wave shuffle + LDS, plain store of the partial.
#pragma unroll
    for (int off = 32; off > 0; off >>= 1)
        acc += __shfl_down(acc, off, 64);

    __shared__ float wsum[4];
    if ((tid & 63) == 0) wsum[tid >> 6] = acc;
    __syncthreads();
    if (tid == 0)
        partials[blk] = wsum[0] + wsum[1] + wsum[2] + wsum[3];
}

// ---------------------------------------------------------------------------
// Stage 2: deterministic final reduction of 1024 block partials (f64).
// ---------------------------------------------------------------------------
__global__ __launch_bounds__(256) void lrl_reduce(
    const float* __restrict__ partials, float* __restrict__ out)
{
    __shared__ double ssum[256];
    ssum[threadIdx.x] = (double)partials[threadIdx.x]
                      + (double)partials[threadIdx.x + 256]
                      + (double)partials[threadIdx.x + 512]
                      + (double)partials[threadIdx.x + 768];
    __syncthreads();
#pragma unroll
    for (int s = 128; s > 0; s >>= 1) {
        if (threadIdx.x < s) ssum[threadIdx.x] += ssum[threadIdx.x + s];
        __syncthreads();
    }
    if (threadIdx.x == 0) out[0] = (float)(ssum[0] / TOTAL_CNT);
}

extern "C" void kernel_launch(void* const* d_in, const int* in_sizes, int n_in,
                              void* d_out, int out_size, void* d_ws, size_t ws_size,
                              hipStream_t stream) {
    const float* disp  = (const float*)d_in[0];
    const float* depth = (const float*)d_in[1];
    const float* vote  = (const float*)d_in[2];
    float* out = (float*)d_out;

    float* partials = (float*)d_ws;        // NBLK floats = 4 KB
    lrl_main<<<NBLK, 256, 0, stream>>>(disp, depth, vote, partials);
    lrl_reduce<<<1, 256, 0, stream>>>(partials, out);
}